// Round 2
// baseline (7615.144 us; speedup 1.0000x reference)
//
#include <hip/hip_runtime.h>

#define NSEG 63

typedef float    f32x4  __attribute__((ext_vector_type(4)));
typedef _Float16 half8  __attribute__((ext_vector_type(8)));
typedef _Float16 half4v __attribute__((ext_vector_type(4)));

#define W2_ELEMS 524288
#define W1_ELEMS 16384
// ws layout (as _Float16*):
//   [0, 524288)          W2 hi frags  [kt][np=i*128+h][kk]
//   [524288, 1048576)    W2 lo frags
//   [1048576, +16384)    W1 hi frags  [kt][n][kk]
//   [1064960, +16384)    W1 lo frags
//   then float b2p[4096] (permuted np = i*128+h)
#define W1H_OFF (2*W2_ELEMS)
#define W1L_OFF (W1H_OFF + W1_ELEMS)
#define B2_OFF  (W1L_OFF + W1_ELEMS)

__device__ __forceinline__ float fast_tanh(float x){
  // tanh(x) = 1 - 2/(1+e^{2x}); exp2-based, ~1ulp fp32
  float e = __builtin_amdgcn_exp2f(x * 2.885390081777927f); // 2*log2(e)
  float r = __builtin_amdgcn_rcpf(e + 1.0f);
  return fmaf(-2.0f, r, 1.0f);
}

__device__ __forceinline__ f32x4 sp4(float v){ f32x4 o = {v,v,v,v}; return o; }

__global__ __launch_bounds__(256) void prep_kernel(const float* __restrict__ W1,
                                                   const float* __restrict__ W2,
                                                   const float* __restrict__ b2,
                                                   _Float16* __restrict__ ws){
  int idx = blockIdx.x*256 + threadIdx.x;
  if (idx < W2_ELEMS){
    int m = idx >> 12, col = idx & 4095;       // W2[m][col], col = h*32+i
    int h = col >> 5,  i = col & 31;
    int kt = m >> 5,   kk = m & 31;
    int np = i*128 + h;
    float w = W2[idx];
    _Float16 hi = (_Float16)w;
    _Float16 lo = (_Float16)(w - (float)hi);
    int pos = (kt*4096 + np)*32 + kk;
    ws[pos] = hi;
    ws[W2_ELEMS + pos] = lo;
  } else if (idx < W2_ELEMS + W1_ELEMS){
    int j = idx - W2_ELEMS;
    int m = j >> 7, n = j & 127;               // W1[m][n]
    float w = W1[j];
    _Float16 hi = (_Float16)w;
    _Float16 lo = (_Float16)(w - (float)hi);
    int pos = ((m>>5)*128 + n)*32 + (m&31);
    ws[W1H_OFF + pos] = hi;
    ws[W1L_OFF + pos] = lo;
  } else if (idx < W2_ELEMS + W1_ELEMS + 4096){
    int j = idx - (W2_ELEMS + W1_ELEMS);       // b2[h*32+i]
    float* b2p = (float*)(ws + B2_OFF);
    b2p[(j & 31)*128 + (j >> 5)] = b2[j];
  }
}

__global__ __launch_bounds__(512, 1) void cde_kernel(
    const float* __restrict__ coeffs,
    const float* __restrict__ W_init, const float* __restrict__ b_init,
    const float* __restrict__ b1,
    const float* __restrict__ W_ro,  const float* __restrict__ b_ro,
    const float* __restrict__ We1,   const float* __restrict__ be1,
    const float* __restrict__ We2,   const float* __restrict__ be2,
    const _Float16* __restrict__ wsw,
    float* __restrict__ out)
{
  __shared__ __align__(16) float zb[16][128];     // z base (fp32 state)
  __shared__ __align__(16) float zacc[16][128];   // RK4 accumulator / evolve tmp
  __shared__ __align__(16) float dzs[16][128];    // current k
  __shared__ __align__(16) _Float16 Zs[16][136];  // stage-z hi (A of GEMM1)
  __shared__ __align__(16) _Float16 Zl[16][136];  // stage-z lo
  __shared__ __align__(16) _Float16 Hs[16][136];  // H hi (A of GEMM2)
  __shared__ __align__(16) _Float16 Hl[16][136];  // H lo
  __shared__ __align__(16) float dXT[3][32][16];  // dX variants, [var][i][b_local]
  __shared__ __align__(16) float ylds[16][32];    // evolve stage y
  __shared__ __align__(16) float b2L[4096];       // permuted b2

  const int tid  = threadIdx.x;
  const int wave = tid >> 6;
  const int lane = tid & 63;
  const int q    = lane >> 4;
  const int ln16 = lane & 15;
  const int row4 = q * 4;
  const int bg   = blockIdx.x * 16;

  // ---- stage b2p into LDS (coalesced) ----
  {
    const float* b2p = (const float*)(wsw + B2_OFF);
    #pragma unroll
    for (int j = 0; j < 8; ++j) b2L[tid + j*512] = b2p[tid + j*512];
  }
  // ---- stage X0 = a[:,0] into dXT[0][i][r] ----
  {
    int r = tid >> 5, i = tid & 31;
    dXT[0][i][r] = coeffs[(size_t)(bg + r)*(NSEG*128) + i];
  }
  __syncthreads();

  // ---- z0 = X0 @ W_init + b_init (fp32), then hi/lo split ----
  {
    int r = tid >> 5, h0 = (tid & 31) * 4;
    f32x4 acc = *(const f32x4*)&b_init[h0];
    #pragma unroll 8
    for (int i = 0; i < 32; ++i){
      float x = dXT[0][i][r];
      f32x4 w = *(const f32x4*)&W_init[i*128 + h0];
      acc += sp4(x) * w;
    }
    *(f32x4*)&zb[r][h0] = acc;
    half4v zh, zl;
    #pragma unroll
    for (int k = 0; k < 4; ++k){
      _Float16 hi = (_Float16)acc[k];
      zh[k] = hi; zl[k] = (_Float16)(acc[k] - (float)hi);
    }
    *(half4v*)&Zs[r][h0] = zh;
    *(half4v*)&Zl[r][h0] = zl;
  }

  // per-wave constants: wave's n-tile (GEMM1) == h-tile (GEMM2)
  const int n0 = wave * 16;
  half8 w1h[4], w1l[4];
  {
    const half8* W1h8 = (const half8*)(wsw + W1H_OFF);
    const half8* W1l8 = (const half8*)(wsw + W1L_OFF);
    #pragma unroll
    for (int kt = 0; kt < 4; ++kt){
      int fi = (kt*128 + n0 + ln16)*4 + q;
      w1h[kt] = W1h8[fi];
      w1l[kt] = W1l8[fi];
    }
  }
  const float b1v = b1[n0 + ln16];
  const half8* Bh8 = (const half8*)wsw;                 // W2 hi plane
  const half8* Bl8 = (const half8*)(wsw + W2_ELEMS);    // W2 lo plane
  const int base8 = (n0 + ln16)*4 + q;                  // in half8 units
  __syncthreads();

  // ================= CDE RK4 scan =================
  for (int t = 0; t < NSEG; ++t){
    // stage dX variants for this step (transposed [i][b])
    {
      int r = tid >> 5, i = tid & 31;
      const float* base = coeffs + (size_t)(bg + r)*(NSEG*128) + (size_t)t*128;
      float bb = base[32+i], cc = base[64+i], dd = base[96+i];
      dXT[0][i][r] = bb;                          // fr=0
      dXT[1][i][r] = bb + cc + 0.75f*dd;          // fr=0.5
      float d4;
      if (t < NSEG-1) d4 = base[128+32+i];        // next seg, fr=0
      else            d4 = bb + 2.0f*cc + 3.0f*dd;// seg 62, fr=1
      dXT[2][i][r] = d4;
    }
    __syncthreads();

    #pragma unroll 1
    for (int s = 0; s < 4; ++s){
      // ---- GEMM1: H = relu(Z @ W1 + b1), split-fp16, 3 chains ----
      {
        half8 a1h[4], a1l[4];
        #pragma unroll
        for (int kt = 0; kt < 4; ++kt){
          a1h[kt] = *(const half8*)&Zs[ln16][kt*32 + q*8];
          a1l[kt] = *(const half8*)&Zl[ln16][kt*32 + q*8];
        }
        f32x4 u0 = sp4(b1v), u1 = sp4(0.0f), u2 = sp4(0.0f);
        #pragma unroll
        for (int kt = 0; kt < 4; ++kt){
          u0 = __builtin_amdgcn_mfma_f32_16x16x32_f16(a1h[kt], w1h[kt], u0, 0, 0, 0);
          u1 = __builtin_amdgcn_mfma_f32_16x16x32_f16(a1l[kt], w1h[kt], u1, 0, 0, 0);
          u2 = __builtin_amdgcn_mfma_f32_16x16x32_f16(a1h[kt], w1l[kt], u2, 0, 0, 0);
        }
        #pragma unroll
        for (int r = 0; r < 4; ++r){
          float hv = u0[r] + u1[r] + u2[r];
          hv = hv > 0.0f ? hv : 0.0f;
          _Float16 hi = (_Float16)hv;
          Hs[row4 + r][n0 + ln16] = hi;
          Hl[row4 + r][n0 + ln16] = (_Float16)(hv - (float)hi);
        }
      }
      __syncthreads();

      // ---- GEMM2 + tanh + dX contraction ----
      half8 a2h[4], a2l[4];
      #pragma unroll
      for (int kt = 0; kt < 4; ++kt){
        a2h[kt] = *(const half8*)&Hs[ln16][kt*32 + q*8];
        a2l[kt] = *(const half8*)&Hl[ln16][kt*32 + q*8];
      }
      const int v = (s == 0) ? 0 : ((s == 3) ? 2 : 1);
      f32x4 dzacc = sp4(0.0f);
      #pragma unroll 4
      for (int i = 0; i < 32; ++i){
        half8 bh0 = Bh8[base8 +             i*512];
        half8 bh1 = Bh8[base8 +   16384 +   i*512];
        half8 bh2 = Bh8[base8 + 2*16384 +   i*512];
        half8 bh3 = Bh8[base8 + 3*16384 +   i*512];
        half8 bl0 = Bl8[base8 +             i*512];
        half8 bl1 = Bl8[base8 +   16384 +   i*512];
        half8 bl2 = Bl8[base8 + 2*16384 +   i*512];
        half8 bl3 = Bl8[base8 + 3*16384 +   i*512];
        float b2v = b2L[i*128 + n0 + ln16];
        f32x4 u0 = sp4(b2v), u1 = sp4(0.0f), u2 = sp4(0.0f);
        u0 = __builtin_amdgcn_mfma_f32_16x16x32_f16(a2h[0], bh0, u0, 0, 0, 0);
        u1 = __builtin_amdgcn_mfma_f32_16x16x32_f16(a2l[0], bh0, u1, 0, 0, 0);
        u2 = __builtin_amdgcn_mfma_f32_16x16x32_f16(a2h[0], bl0, u2, 0, 0, 0);
        u0 = __builtin_amdgcn_mfma_f32_16x16x32_f16(a2h[1], bh1, u0, 0, 0, 0);
        u1 = __builtin_amdgcn_mfma_f32_16x16x32_f16(a2l[1], bh1, u1, 0, 0, 0);
        u2 = __builtin_amdgcn_mfma_f32_16x16x32_f16(a2h[1], bl1, u2, 0, 0, 0);
        u0 = __builtin_amdgcn_mfma_f32_16x16x32_f16(a2h[2], bh2, u0, 0, 0, 0);
        u1 = __builtin_amdgcn_mfma_f32_16x16x32_f16(a2l[2], bh2, u1, 0, 0, 0);
        u2 = __builtin_amdgcn_mfma_f32_16x16x32_f16(a2h[2], bl2, u2, 0, 0, 0);
        u0 = __builtin_amdgcn_mfma_f32_16x16x32_f16(a2h[3], bh3, u0, 0, 0, 0);
        u1 = __builtin_amdgcn_mfma_f32_16x16x32_f16(a2l[3], bh3, u1, 0, 0, 0);
        u2 = __builtin_amdgcn_mfma_f32_16x16x32_f16(a2h[3], bl3, u2, 0, 0, 0);
        f32x4 dxv = *(const f32x4*)&dXT[v][i][row4];
        #pragma unroll
        for (int r = 0; r < 4; ++r)
          dzacc[r] = fmaf(fast_tanh(u0[r] + u1[r] + u2[r]), dxv[r], dzacc[r]);
      }
      #pragma unroll
      for (int r = 0; r < 4; ++r)
        dzs[row4 + r][n0 + ln16] = dzacc[r];
      __syncthreads();

      // ---- RK4 elementwise update (fp32 state) ----
      {
        int r = tid >> 5, h0 = (tid & 31) * 4;
        f32x4 dz4 = *(const f32x4*)&dzs[r][h0];
        f32x4 zb4 = *(const f32x4*)&zb[r][h0];
        f32x4 za;
        if (s == 0) za = dz4;
        else {
          float w = (s == 3) ? 1.0f : 2.0f;
          za = *(const f32x4*)&zacc[r][h0] + sp4(w) * dz4;
        }
        *(f32x4*)&zacc[r][h0] = za;
        f32x4 zs4;
        if (s == 3){
          zb4 = zb4 + za * sp4(1.0f/6.0f);
          *(f32x4*)&zb[r][h0] = zb4;
          zs4 = zb4;
        } else if (s == 2) zs4 = zb4 + dz4;
        else               zs4 = zb4 + sp4(0.5f) * dz4;
        half4v zh, zl;
        #pragma unroll
        for (int k = 0; k < 4; ++k){
          _Float16 hi = (_Float16)zs4[k];
          zh[k] = hi; zl[k] = (_Float16)(zs4[k] - (float)hi);
        }
        *(half4v*)&Zs[r][h0] = zh;
        *(half4v*)&Zl[r][h0] = zl;
      }
      __syncthreads();
    }
  }

  // ================= readout + evolve head (fp32 scalar) =================
  const int r = tid >> 5, c = tid & 31;
  float yv = b_ro[c];
  #pragma unroll 8
  for (int h = 0; h < 128; ++h)
    yv = fmaf(zb[r][h], W_ro[h*32 + c], yv);
  ylds[r][c] = yv;
  float yb = yv, yac = 0.0f;
  __syncthreads();

  for (int st = 0; st < 10; ++st){
    #pragma unroll 1
    for (int s = 0; s < 4; ++s){
      // tmp = tanh(ys @ We1 + be1) -> zacc (reused)
      {
        int rr = tid >> 5, m0 = (tid & 31) * 4;
        f32x4 acc = *(const f32x4*)&be1[m0];
        #pragma unroll 4
        for (int i = 0; i < 32; ++i){
          float x = ylds[rr][i];
          acc += sp4(x) * (*(const f32x4*)&We1[i*128 + m0]);
        }
        f32x4 tt;
        tt.x = fast_tanh(acc.x); tt.y = fast_tanh(acc.y);
        tt.z = fast_tanh(acc.z); tt.w = fast_tanh(acc.w);
        *(f32x4*)&zacc[rr][m0] = tt;
      }
      __syncthreads();
      float kv = be2[c];
      #pragma unroll 8
      for (int m = 0; m < 128; ++m)
        kv = fmaf(zacc[r][m], We2[m*32 + c], kv);
      float ysn;
      if      (s == 0){ yac = kv;        ysn = yb + 0.25f*kv; }
      else if (s == 1){ yac += 2.0f*kv;  ysn = yb + 0.25f*kv; }
      else if (s == 2){ yac += 2.0f*kv;  ysn = yb + 0.5f*kv;  }
      else            { yac += kv;       yb  = yb + yac*(1.0f/12.0f); ysn = yb; }
      ylds[r][c] = ysn;
      __syncthreads();
    }
  }
  out[(size_t)(bg + r)*32 + c] = yb;
}

extern "C" void kernel_launch(void* const* d_in, const int* in_sizes, int n_in,
                              void* d_out, int out_size, void* d_ws, size_t ws_size,
                              hipStream_t stream){
  const float* coeffs = (const float*)d_in[0];
  const float* W_init = (const float*)d_in[1];
  const float* b_init = (const float*)d_in[2];
  const float* W1     = (const float*)d_in[3];
  const float* b1     = (const float*)d_in[4];
  const float* W2     = (const float*)d_in[5];
  const float* b2     = (const float*)d_in[6];
  const float* W_ro   = (const float*)d_in[7];
  const float* b_ro   = (const float*)d_in[8];
  const float* We1    = (const float*)d_in[9];
  const float* be1    = (const float*)d_in[10];
  const float* We2    = (const float*)d_in[11];
  const float* be2    = (const float*)d_in[12];
  _Float16* ws        = (_Float16*)d_ws;

  // 524288 + 16384 + 4096 = 544768 items -> 2128 blocks of 256
  prep_kernel<<<2128, 256, 0, stream>>>(W1, W2, b2, ws);
  cde_kernel<<<128, 512, 0, stream>>>(coeffs, W_init, b_init, b1, W_ro, b_ro,
                                      We1, be1, We2, be2, ws, (float*)d_out);
}